// Round 1
// 276.787 us; speedup vs baseline: 1.0134x; 1.0134x over previous
//
#include <hip/hip_runtime.h>

// Problem constants (fp32 throughout):
//   y:          (4, 64, 8, 16)            = 32768
//   pairwise_g: (4, 64, 64, 8, 8, 48)     = 50331648  (201.3 MB -> HBM-bound)
//   Wy: (32,1)  by: (1,)  Wg: (48,1)  bg: (1,)
//   out k: (4, 64, 64, 8, 8, 1)           = 1048576
//
// k[b,p1,p2,s1,s2] = dot(g[b,p1,p2,s1,s2,:], Wg) + bg + by
//                    + dot(y[b,p2,s2,:], Wy[:16])     (a-term, indexed p2,s2)
//                    + dot(y[b,p1,s1,:], Wy[16:])     (c-term, indexed p1,s1)
//
// Single fused kernel. One block per (b,p1,p2): 64 outputs, 256 threads,
// 4 lanes per output.
//
// Slot permutation for perfect coalescing: lane t of a 4-group handles
// float4 slots {t, t+4, t+8} of its output's 12 float4s. Per load
// instruction j, the 4 lanes of a group cover one full, aligned 64-B line
// (o*192 + j*64 + t*16) -- every memory transaction is 100% consumed,
// 3x fewer line-requests than the previous {3t,3t+1,3t+2} layout which
// strided 16B chunks at 48B across the whole 3-KB window.

#define NOUT 1048576         // B*P*P*S*S

__global__ __launch_bounds__(256) void fused_kernel(
    const float* __restrict__ g,
    const float* __restrict__ Wg,
    const float* __restrict__ y,
    const float* __restrict__ Wy,
    const float* __restrict__ by,
    const float* __restrict__ bg,
    float* __restrict__ out) {
    __shared__ float ac[16];   // [0:8] = a(s2) (+by+bg), [8:16] = c(s1)

    int blk = blockIdx.x;      // blk = ((b*64 + p1)*64 + p2)
    int tid = threadIdx.x;
    int p2 = blk & 63;
    int p1 = (blk >> 6) & 63;
    int b  = blk >> 12;

    // a/c pre-terms: 16 dot-products of length 16 over y (L2/L3-resident,
    // 128 KB total). threads 0..7 -> a[s2], threads 8..15 -> c[s1].
    if (tid < 16) {
        int s = tid & 7;
        int row = (tid < 8) ? (((b << 6) + p2) << 3) + s    // y[b,p2,s,:]
                            : (((b << 6) + p1) << 3) + s;   // y[b,p1,s,:]
        const float4* yv = reinterpret_cast<const float4*>(y + row * 16);
        const float4* wv = reinterpret_cast<const float4*>(Wy + ((tid < 8) ? 0 : 16));
        float acc = 0.f;
#pragma unroll
        for (int j = 0; j < 4; ++j) {
            float4 v = yv[j];
            float4 w = wv[j];
            acc += v.x * w.x + v.y * w.y + v.z * w.z + v.w * w.w;
        }
        ac[tid] = acc + ((tid < 8) ? (by[0] + bg[0]) : 0.f);
    }
    __syncthreads();

    int o_local = tid >> 2;            // 0..63  (= s1*8 + s2)
    int t = tid & 3;                   // sub-lane within the 4-lane group
    size_t o = (size_t)blk * 64 + o_local;

    const float4* gv = reinterpret_cast<const float4*>(g + o * 48);
    const float4* wv = reinterpret_cast<const float4*>(Wg);

    float s = 0.f;
#pragma unroll
    for (int j = 0; j < 3; ++j) {
        float4 v = gv[t + 4 * j];      // slots {t, t+4, t+8}
        float4 w = wv[t + 4 * j];
        s += v.x * w.x + v.y * w.y + v.z * w.z + v.w * w.w;
    }
    // reduce across the 4-lane group (wave64: groups are lane-contiguous)
    s += __shfl_xor(s, 1);
    s += __shfl_xor(s, 2);

    if (t == 0) {
        int s2 = o_local & 7;
        int s1 = o_local >> 3;
        out[o] = s + ac[s2] + ac[8 + s1];
    }
}

extern "C" void kernel_launch(void* const* d_in, const int* in_sizes, int n_in,
                              void* d_out, int out_size, void* d_ws, size_t ws_size,
                              hipStream_t stream) {
    const float* y  = (const float*)d_in[0];
    const float* g  = (const float*)d_in[1];
    const float* Wy = (const float*)d_in[2];
    const float* by = (const float*)d_in[3];
    const float* Wg = (const float*)d_in[4];
    const float* bg = (const float*)d_in[5];
    float* out = (float*)d_out;

    // 64 outputs per block -> NOUT/64 = 16384 blocks, one per (b,p1,p2)
    fused_kernel<<<NOUT / 64, 256, 0, stream>>>(g, Wg, y, Wy, by, bg, out);
}